// Round 1
// baseline (258.446 us; speedup 1.0000x reference)
//
#include <hip/hip_runtime.h>
#include <hip/hip_bf16.h>

// Problem constants: B=2, S=2048, D=1024, H=16, dk=64
#define S_LEN 2048
#define D_DIM 1024
#define N_HEADS 16
#define M_ROWS 4096  // B*S

typedef __bf16 bf16x8 __attribute__((ext_vector_type(8)));
typedef float f32x4 __attribute__((ext_vector_type(4)));
typedef unsigned short ushortx8 __attribute__((ext_vector_type(8)));

__device__ __forceinline__ unsigned short f2bf(float f) {
  unsigned int u = __builtin_bit_cast(unsigned int, f);
  u += 0x7fffu + ((u >> 16) & 1u);   // RNE
  return (unsigned short)(u >> 16);
}

__device__ __forceinline__ bf16x8 load8(const unsigned short* p) {
  return __builtin_bit_cast(bf16x8, *(const ushortx8*)p);
}

__device__ __forceinline__ void gload16(const unsigned short* g, unsigned short* l) {
  __builtin_amdgcn_global_load_lds((const __attribute__((address_space(1))) void*)g,
                                   (__attribute__((address_space(3))) void*)l,
                                   16, 0, 0);
}

// ---------------- fp32 -> bf16 convert ----------------
__global__ void cvt_kernel(const float* __restrict__ src, unsigned short* __restrict__ dst, int n4) {
  int i = blockIdx.x * blockDim.x + threadIdx.x;
  if (i < n4) {
    float4 f = ((const float4*)src)[i];
    unsigned short a = f2bf(f.x), b = f2bf(f.y), c = f2bf(f.z), d = f2bf(f.w);
    unsigned long long packed = (unsigned long long)a | ((unsigned long long)b << 16)
                              | ((unsigned long long)c << 32) | ((unsigned long long)d << 48);
    ((unsigned long long*)dst)[i] = packed;
  }
}

// ---------------- bf16 GEMM: C = A[M,K] * B[N,K]^T ----------------
// mode 0: fp32 row-major [M][N] output
// mode 1: bf16 [B,H,S,64] output (Q,K)
// mode 2: bf16 [B,H,64,S] output (V transposed)
__global__ __launch_bounds__(256) void gemm_bt(
    const unsigned short* __restrict__ A,
    const unsigned short* __restrict__ B0,
    const unsigned short* __restrict__ B1,
    const unsigned short* __restrict__ B2,
    void* __restrict__ C0, void* __restrict__ C1, void* __restrict__ C2,
    int M, int N, int K, int modesel)
{
  __shared__ __align__(16) unsigned short At[128 * 64];
  __shared__ __align__(16) unsigned short Bt[128 * 64];

  const int z = blockIdx.z;
  const unsigned short* Bp = (z == 0) ? B0 : (z == 1) ? B1 : B2;
  void* Cp = (z == 0) ? C0 : (z == 1) ? C1 : C2;
  const int mode = (modesel == 0) ? 0 : ((z == 2) ? 2 : 1);

  const int tid = threadIdx.x;
  const int lane = tid & 63, wave = tid >> 6;
  const int bm = blockIdx.y * 128, bn = blockIdx.x * 128;
  const int wr = wave >> 1, wc = wave & 1;           // 2x2 wave grid, 64x64 each
  const int cl = lane & 15, g = lane >> 4;
  // staging: chunks of 512 elems (8 rows x 64 elems); pre-swizzled global slot
  const int ci = lane >> 3, si = lane & 7;
  const int sg = si ^ (ci & 7);

  f32x4 acc[4][4] = {};

  for (int kb = 0; kb < K; kb += 64) {
    __syncthreads();
#pragma unroll
    for (int cc = 0; cc < 4; ++cc) {
      int chunk = wave * 4 + cc;
      int row = chunk * 8 + ci;
      gload16(A  + (size_t)(bm + row) * K + kb + sg * 8, &At[chunk * 512]);
      gload16(Bp + (size_t)(bn + row) * K + kb + sg * 8, &Bt[chunk * 512]);
    }
    __syncthreads();
#pragma unroll
    for (int kc = 0; kc < 2; ++kc) {
      bf16x8 af[4], bfr[4];
#pragma unroll
      for (int mi = 0; mi < 4; ++mi) {
        int row = wr * 64 + mi * 16 + cl;
        int slot = (kc * 4 + g) ^ (row & 7);
        af[mi] = load8(&At[row * 64 + slot * 8]);
      }
#pragma unroll
      for (int ni = 0; ni < 4; ++ni) {
        int row = wc * 64 + ni * 16 + cl;
        int slot = (kc * 4 + g) ^ (row & 7);
        bfr[ni] = load8(&Bt[row * 64 + slot * 8]);
      }
#pragma unroll
      for (int mi = 0; mi < 4; ++mi)
#pragma unroll
        for (int ni = 0; ni < 4; ++ni)
          acc[mi][ni] = __builtin_amdgcn_mfma_f32_16x16x32_bf16(af[mi], bfr[ni], acc[mi][ni], 0, 0, 0);
    }
  }

  // epilogue: C row = (lane>>4)*4 + reg, col = lane&15 (verified m89/m91 layout)
  const int r0 = g * 4;
#pragma unroll
  for (int mi = 0; mi < 4; ++mi) {
#pragma unroll
    for (int ni = 0; ni < 4; ++ni) {
      int mg = bm + wr * 64 + mi * 16 + r0;
      int ng = bn + wc * 64 + ni * 16 + cl;
#pragma unroll
      for (int r = 0; r < 4; ++r) {
        float v = acc[mi][ni][r];
        int m = mg + r;
        if (mode == 0) {
          ((float*)Cp)[(size_t)m * N + ng] = v;
        } else {
          int b = m >> 11, s = m & 2047;        // S=2048
          int h = ng >> 6, d = ng & 63;         // dk=64
          unsigned short* o = (unsigned short*)Cp;
          if (mode == 1) o[((size_t)(b * N_HEADS + h) * S_LEN + s) * 64 + d] = f2bf(v);
          else           o[((size_t)(b * N_HEADS + h) * 64 + d) * S_LEN + s] = f2bf(v);
        }
      }
    }
  }
}

// ---------------- causal flash attention ----------------
// Q,K: [BH][S][64] bf16; Vt: [BH][64][S] bf16; out: [B][S][H*64] bf16
__global__ __launch_bounds__(256) void attn_kernel(
    const unsigned short* __restrict__ Qg,
    const unsigned short* __restrict__ Kg,
    const unsigned short* __restrict__ Vtg,
    unsigned short* __restrict__ Og)
{
  __shared__ __align__(16) unsigned short Kt[32 * 64];   // [key][dk]
  __shared__ __align__(16) unsigned short Vt[64 * 32];   // [dk][key]
  __shared__ __align__(16) unsigned short Pt[4][16 * 32];

  const int tid = threadIdx.x;
  const int lane = tid & 63, wave = tid >> 6;
  const int bh = blockIdx.y;
  const int qbase = blockIdx.x * 64;
  const int qt = qbase + wave * 16;
  const int cl = lane & 15, g = lane >> 4;

  // Q fragments live in registers for the whole kernel
  const unsigned short* qrow = Qg + ((size_t)bh * S_LEN + qt + cl) * 64;
  bf16x8 aq0 = load8(qrow + g * 8);
  bf16x8 aq1 = load8(qrow + 32 + g * 8);

  f32x4 o[4] = {};
  float mrow[4] = {-1e30f, -1e30f, -1e30f, -1e30f};
  float lrow[4] = {0.f, 0.f, 0.f, 0.f};

  // staging swizzle precompute
  const int kci = lane >> 3, ksg = (lane & 7) ^ ((lane >> 3) & 7);   // K tile: rows of 64 elems
  const int vci = lane >> 2, vsg = (lane & 3) ^ ((lane >> 3) & 3);   // Vt tile: rows of 32 elems

  const int nkb = (qbase + 64) / 32;
  for (int kb = 0; kb < nkb; ++kb) {
    const int kbase = kb * 32;
    __syncthreads();
    {
      int krow = wave * 8 + kci;
      gload16(Kg + ((size_t)bh * S_LEN + kbase + krow) * 64 + ksg * 8, &Kt[wave * 512]);
      int vrow = wave * 16 + vci;
      gload16(Vtg + ((size_t)bh * 64 + vrow) * S_LEN + kbase + vsg * 8, &Vt[wave * 512]);
    }
    __syncthreads();

    if (kbase <= qt + 15) {
      // scores: S = Q * K^T, two 16-key column tiles
      f32x4 c0 = {}, c1 = {};
      {
        int row0 = cl, row1 = 16 + cl;
        bf16x8 bk;
        bk = load8(&Kt[row0 * 64 + ((g) ^ (row0 & 7)) * 8]);
        c0 = __builtin_amdgcn_mfma_f32_16x16x32_bf16(aq0, bk, c0, 0, 0, 0);
        bk = load8(&Kt[row0 * 64 + ((4 + g) ^ (row0 & 7)) * 8]);
        c0 = __builtin_amdgcn_mfma_f32_16x16x32_bf16(aq1, bk, c0, 0, 0, 0);
        bk = load8(&Kt[row1 * 64 + ((g) ^ (row1 & 7)) * 8]);
        c1 = __builtin_amdgcn_mfma_f32_16x16x32_bf16(aq0, bk, c1, 0, 0, 0);
        bk = load8(&Kt[row1 * 64 + ((4 + g) ^ (row1 & 7)) * 8]);
        c1 = __builtin_amdgcn_mfma_f32_16x16x32_bf16(aq1, bk, c1, 0, 0, 0);
      }
      // scale + causal mask
#pragma unroll
      for (int r = 0; r < 4; ++r) {
        int q = qt + g * 4 + r;
        float s0 = c0[r] * 0.125f; if (kbase + cl > q)      s0 = -1e30f;
        float s1 = c1[r] * 0.125f; if (kbase + 16 + cl > q) s1 = -1e30f;
        c0[r] = s0; c1[r] = s1;
      }
      // row max over 32 keys (16-lane butterfly; rows live in lane&15 slices)
      float pm[4];
#pragma unroll
      for (int r = 0; r < 4; ++r) pm[r] = fmaxf(c0[r], c1[r]);
#pragma unroll
      for (int msk = 1; msk < 16; msk <<= 1)
#pragma unroll
        for (int r = 0; r < 4; ++r) pm[r] = fmaxf(pm[r], __shfl_xor(pm[r], msk, 64));
      // online softmax update
      float al[4];
#pragma unroll
      for (int r = 0; r < 4; ++r) {
        float mn = fmaxf(mrow[r], pm[r]);
        al[r] = __expf(mrow[r] - mn);
        mrow[r] = mn;
      }
#pragma unroll
      for (int r = 0; r < 4; ++r) {
        c0[r] = __expf(c0[r] - mrow[r]);
        c1[r] = __expf(c1[r] - mrow[r]);
      }
      float rs[4];
#pragma unroll
      for (int r = 0; r < 4; ++r) rs[r] = c0[r] + c1[r];
#pragma unroll
      for (int msk = 1; msk < 16; msk <<= 1)
#pragma unroll
        for (int r = 0; r < 4; ++r) rs[r] += __shfl_xor(rs[r], msk, 64);
#pragma unroll
      for (int r = 0; r < 4; ++r) lrow[r] = lrow[r] * al[r] + rs[r];
#pragma unroll
      for (int nt = 0; nt < 4; ++nt)
#pragma unroll
        for (int r = 0; r < 4; ++r) o[nt][r] *= al[r];

      // P through per-wave LDS: C-layout -> A-fragment layout (swizzled)
      unsigned short* P = &Pt[wave][0];
#pragma unroll
      for (int r = 0; r < 4; ++r) {
        int row = g * 4 + r;
        int sw = (row >> 1) & 3;
        P[row * 32 + (((cl >> 3) ^ sw)) * 8 + (cl & 7)] = f2bf(c0[r]);
        int col = 16 + cl;
        P[row * 32 + (((col >> 3) ^ sw)) * 8 + (col & 7)] = f2bf(c1[r]);
      }
      bf16x8 ap = load8(&P[cl * 32 + ((g ^ ((cl >> 1) & 3))) * 8]);
      // PV: o += P[16x32] * V[32x64]
#pragma unroll
      for (int nt = 0; nt < 4; ++nt) {
        int vr = nt * 16 + cl;
        bf16x8 bv = load8(&Vt[vr * 32 + ((g ^ ((vr >> 1) & 3))) * 8]);
        o[nt] = __builtin_amdgcn_mfma_f32_16x16x32_bf16(ap, bv, o[nt], 0, 0, 0);
      }
    }
  }

  // normalize + write [B][S][H*64]
  const int b = bh >> 4, h = bh & 15;
#pragma unroll
  for (int r = 0; r < 4; ++r) {
    int q = qt + g * 4 + r;
    float inv = 1.0f / lrow[r];
    size_t base = ((size_t)(b * S_LEN + q)) * D_DIM + h * 64;
#pragma unroll
    for (int nt = 0; nt < 4; ++nt)
      Og[base + nt * 16 + cl] = f2bf(o[nt][r] * inv);
  }
}

extern "C" void kernel_launch(void* const* d_in, const int* in_sizes, int n_in,
                              void* d_out, int out_size, void* d_ws, size_t ws_size,
                              hipStream_t stream) {
  const float* x  = (const float*)d_in[0];
  const float* Wq = (const float*)d_in[1];
  const float* Wk = (const float*)d_in[2];
  const float* Wv = (const float*)d_in[3];
  const float* Wo = (const float*)d_in[4];

  const int M = M_ROWS, D = D_DIM;

  unsigned short* ws  = (unsigned short*)d_ws;
  unsigned short* xb  = ws;                          // M*D
  unsigned short* wqb = xb  + (size_t)M * D;         // D*D
  unsigned short* wkb = wqb + (size_t)D * D;
  unsigned short* wvb = wkb + (size_t)D * D;
  unsigned short* wob = wvb + (size_t)D * D;
  unsigned short* qb  = wob + (size_t)D * D;         // M*D  [B,H,S,64]
  unsigned short* kbf = qb  + (size_t)M * D;         // M*D  [B,H,S,64]
  unsigned short* vtb = kbf + (size_t)M * D;         // M*D  [B,H,64,S]
  unsigned short* aob = vtb + (size_t)M * D;         // M*D  [B,S,D]

  // 1) convert inputs to bf16
  cvt_kernel<<<(M * D / 4 + 255) / 256, 256, 0, stream>>>(x,  xb,  M * D / 4);
  cvt_kernel<<<(D * D / 4 + 255) / 256, 256, 0, stream>>>(Wq, wqb, D * D / 4);
  cvt_kernel<<<(D * D / 4 + 255) / 256, 256, 0, stream>>>(Wk, wkb, D * D / 4);
  cvt_kernel<<<(D * D / 4 + 255) / 256, 256, 0, stream>>>(Wv, wvb, D * D / 4);
  cvt_kernel<<<(D * D / 4 + 255) / 256, 256, 0, stream>>>(Wo, wob, D * D / 4);

  // 2) fused QKV projections
  dim3 gq(D / 128, M / 128, 3);
  gemm_bt<<<gq, 256, 0, stream>>>(xb, wqb, wkb, wvb, qb, kbf, vtb, M, D, D, 1);

  // 3) causal flash attention
  dim3 ga(S_LEN / 64, 2 * N_HEADS);
  attn_kernel<<<ga, 256, 0, stream>>>(qb, kbf, vtb, aob);

  // 4) output projection -> fp32 d_out
  dim3 go(D / 128, M / 128, 1);
  gemm_bt<<<go, 256, 0, stream>>>(aob, wob, wob, wob, d_out, d_out, d_out, M, D, D, 0);
}

// Round 2
// 205.792 us; speedup vs baseline: 1.2559x; 1.2559x over previous
//
#include <hip/hip_runtime.h>
#include <hip/hip_bf16.h>

// Problem constants: B=2, S=2048, D=1024, H=16, dk=64
#define S_LEN 2048
#define D_DIM 1024
#define N_HEADS 16
#define M_ROWS 4096  // B*S

typedef __bf16 bf16x8 __attribute__((ext_vector_type(8)));
typedef float f32x4 __attribute__((ext_vector_type(4)));
typedef unsigned short ushortx8 __attribute__((ext_vector_type(8)));

__device__ __forceinline__ unsigned short f2bf(float f) {
  unsigned int u = __builtin_bit_cast(unsigned int, f);
  u += 0x7fffu + ((u >> 16) & 1u);   // RNE
  return (unsigned short)(u >> 16);
}

__device__ __forceinline__ bf16x8 load8(const unsigned short* p) {
  return __builtin_bit_cast(bf16x8, *(const ushortx8*)p);
}

__device__ __forceinline__ void gload16(const unsigned short* g, unsigned short* l) {
  __builtin_amdgcn_global_load_lds((const __attribute__((address_space(1))) void*)g,
                                   (__attribute__((address_space(3))) void*)l,
                                   16, 0, 0);
}

// ---------------- fp32 -> bf16 convert (fused: x + 4 weights) ----------------
__global__ void cvt5_kernel(const float* __restrict__ s0, const float* __restrict__ s1,
                            const float* __restrict__ s2, const float* __restrict__ s3,
                            const float* __restrict__ s4,
                            unsigned short* __restrict__ d0, unsigned short* __restrict__ d1,
                            unsigned short* __restrict__ d2, unsigned short* __restrict__ d3,
                            unsigned short* __restrict__ d4,
                            int n4x, int n4w) {
  const int y = blockIdx.y;
  const float* s = (y == 0) ? s0 : (y == 1) ? s1 : (y == 2) ? s2 : (y == 3) ? s3 : s4;
  unsigned short* d = (y == 0) ? d0 : (y == 1) ? d1 : (y == 2) ? d2 : (y == 3) ? d3 : d4;
  const int n4 = (y == 0) ? n4x : n4w;
  int i = blockIdx.x * blockDim.x + threadIdx.x;
  if (i < n4) {
    float4 f = ((const float4*)s)[i];
    unsigned short a = f2bf(f.x), b = f2bf(f.y), c = f2bf(f.z), dd = f2bf(f.w);
    unsigned long long packed = (unsigned long long)a | ((unsigned long long)b << 16)
                              | ((unsigned long long)c << 32) | ((unsigned long long)dd << 48);
    ((unsigned long long*)d)[i] = packed;
  }
}

// ---------------- bf16 GEMM: C = A[M,K] * B[N,K]^T ----------------
// mode 0: fp32 row-major [M][N] output
// mode 1: bf16 [B,H,S,64] output (Q,K); Q (z==0) pre-scaled by 1/sqrt(dk)
// mode 2: bf16 [B,H,64,S] output (V transposed)
__global__ __launch_bounds__(256) void gemm_bt(
    const unsigned short* __restrict__ A,
    const unsigned short* __restrict__ B0,
    const unsigned short* __restrict__ B1,
    const unsigned short* __restrict__ B2,
    void* __restrict__ C0, void* __restrict__ C1, void* __restrict__ C2,
    int M, int N, int K, int modesel)
{
  __shared__ __align__(16) unsigned short At[128 * 64];
  __shared__ __align__(16) unsigned short Bt[128 * 64];

  const int z = blockIdx.z;
  const unsigned short* Bp = (z == 0) ? B0 : (z == 1) ? B1 : B2;
  void* Cp = (z == 0) ? C0 : (z == 1) ? C1 : C2;
  const int mode = (modesel == 0) ? 0 : ((z == 2) ? 2 : 1);
  const float escale = (modesel == 1 && z == 0) ? 0.125f : 1.0f;

  const int tid = threadIdx.x;
  const int lane = tid & 63, wave = tid >> 6;
  const int bm = blockIdx.y * 128, bn = blockIdx.x * 128;
  const int wr = wave >> 1, wc = wave & 1;           // 2x2 wave grid, 64x64 each
  const int cl = lane & 15, g = lane >> 4;
  // staging: chunks of 512 elems (8 rows x 64 elems); pre-swizzled global slot
  const int ci = lane >> 3, si = lane & 7;
  const int sg = si ^ (ci & 7);

  f32x4 acc[4][4] = {};

  for (int kb = 0; kb < K; kb += 64) {
    __syncthreads();
#pragma unroll
    for (int cc = 0; cc < 4; ++cc) {
      int chunk = wave * 4 + cc;
      int row = chunk * 8 + ci;
      gload16(A  + (size_t)(bm + row) * K + kb + sg * 8, &At[chunk * 512]);
      gload16(Bp + (size_t)(bn + row) * K + kb + sg * 8, &Bt[chunk * 512]);
    }
    __syncthreads();
#pragma unroll
    for (int kc = 0; kc < 2; ++kc) {
      bf16x8 af[4], bfr[4];
#pragma unroll
      for (int mi = 0; mi < 4; ++mi) {
        int row = wr * 64 + mi * 16 + cl;
        int slot = (kc * 4 + g) ^ (row & 7);
        af[mi] = load8(&At[row * 64 + slot * 8]);
      }
#pragma unroll
      for (int ni = 0; ni < 4; ++ni) {
        int row = wc * 64 + ni * 16 + cl;
        int slot = (kc * 4 + g) ^ (row & 7);
        bfr[ni] = load8(&Bt[row * 64 + slot * 8]);
      }
#pragma unroll
      for (int mi = 0; mi < 4; ++mi)
#pragma unroll
        for (int ni = 0; ni < 4; ++ni)
          acc[mi][ni] = __builtin_amdgcn_mfma_f32_16x16x32_bf16(af[mi], bfr[ni], acc[mi][ni], 0, 0, 0);
    }
  }

  // epilogue: C row = (lane>>4)*4 + reg, col = lane&15
  const int r0 = g * 4;
#pragma unroll
  for (int mi = 0; mi < 4; ++mi) {
#pragma unroll
    for (int ni = 0; ni < 4; ++ni) {
      int mg = bm + wr * 64 + mi * 16 + r0;
      int ng = bn + wc * 64 + ni * 16 + cl;
#pragma unroll
      for (int r = 0; r < 4; ++r) {
        float v = acc[mi][ni][r] * escale;
        int m = mg + r;
        if (mode == 0) {
          ((float*)Cp)[(size_t)m * N + ng] = v;
        } else {
          int b = m >> 11, s = m & 2047;        // S=2048
          int h = ng >> 6, d = ng & 63;         // dk=64
          unsigned short* o = (unsigned short*)Cp;
          if (mode == 1) o[((size_t)(b * N_HEADS + h) * S_LEN + s) * 64 + d] = f2bf(v);
          else           o[((size_t)(b * N_HEADS + h) * 64 + d) * S_LEN + s] = f2bf(v);
        }
      }
    }
  }
}

// ---------------- causal flash attention, no-staging (L2-resident K/V) ------
// Q,K: [BH][S][64] bf16 (Q pre-scaled); Vt: [BH][64][S] bf16; out: [B][S][H*64] bf16
// 512 blocks x 256 thr; each wave independent: 32 q-rows, 32-key blocks, no barriers.
__global__ __launch_bounds__(256) void attn_kernel(
    const unsigned short* __restrict__ Qg,
    const unsigned short* __restrict__ Kg,
    const unsigned short* __restrict__ Vtg,
    unsigned short* __restrict__ Og)
{
  __shared__ __align__(16) unsigned short Pt[4][32 * 32];   // per-wave P transpose buffer

  const int tid = threadIdx.x;
  const int lane = tid & 63, wave = tid >> 6;
  const int cl = lane & 15, g = lane >> 4;

  // XCD-contiguous swizzle: 512 wgs, 64 per XCD -> 4 heads per XCD (K/V L2-resident)
  const int wg = (blockIdx.x & 7) * 64 + (blockIdx.x >> 3);
  const int bh = wg >> 4;          // 32 (b,h) pairs
  const int qc = wg & 15;          // 16 q-chunks of 128 rows
  const int qt = qc * 128 + wave * 32;

  const size_t qkb = (size_t)bh * S_LEN;

  // Q fragments in registers for the whole kernel (already scaled by 1/8)
  bf16x8 aq[2][2];
#pragma unroll
  for (int rt = 0; rt < 2; ++rt)
#pragma unroll
    for (int kh = 0; kh < 2; ++kh)
      aq[rt][kh] = load8(Qg + (qkb + qt + rt * 16 + cl) * 64 + kh * 32 + g * 8);

  f32x4 o[2][4] = {};
  float mrow[2][4], lrow[2][4];
#pragma unroll
  for (int rt = 0; rt < 2; ++rt)
#pragma unroll
    for (int r = 0; r < 4; ++r) { mrow[rt][r] = -1e30f; lrow[rt][r] = 0.f; }

  const int nkb = qt / 32 + 1;
  for (int kb = 0; kb < nkb; ++kb) {
    const int kbase = kb * 32;

    // K fragments: coalesced 16B/lane from L2
    bf16x8 bk[2][2];
#pragma unroll
    for (int ct = 0; ct < 2; ++ct)
#pragma unroll
      for (int kh = 0; kh < 2; ++kh)
        bk[ct][kh] = load8(Kg + (qkb + kbase + ct * 16 + cl) * 64 + kh * 32 + g * 8);
    // V^T fragments (B-operand of PV) straight from L2
    bf16x8 bv[4];
#pragma unroll
    for (int nt = 0; nt < 4; ++nt)
      bv[nt] = load8(Vtg + ((size_t)bh * 64 + nt * 16 + cl) * S_LEN + kbase + g * 8);

    // scores: 32 q-rows x 32 keys
    f32x4 c[2][2] = {};
#pragma unroll
    for (int rt = 0; rt < 2; ++rt)
#pragma unroll
      for (int ct = 0; ct < 2; ++ct) {
        c[rt][ct] = __builtin_amdgcn_mfma_f32_16x16x32_bf16(aq[rt][0], bk[ct][0], c[rt][ct], 0, 0, 0);
        c[rt][ct] = __builtin_amdgcn_mfma_f32_16x16x32_bf16(aq[rt][1], bk[ct][1], c[rt][ct], 0, 0, 0);
      }

    if (kb == nkb - 1) {   // only the diagonal block needs the causal mask
#pragma unroll
      for (int rt = 0; rt < 2; ++rt)
#pragma unroll
        for (int ct = 0; ct < 2; ++ct) {
          int key = kbase + ct * 16 + cl;
#pragma unroll
          for (int r = 0; r < 4; ++r) {
            int row = qt + rt * 16 + g * 4 + r;
            if (key > row) c[rt][ct][r] = -1e30f;
          }
        }
    }

    // row max (16-lane butterfly; rows live across cl with fixed g)
    float pm[2][4];
#pragma unroll
    for (int rt = 0; rt < 2; ++rt)
#pragma unroll
      for (int r = 0; r < 4; ++r) pm[rt][r] = fmaxf(c[rt][0][r], c[rt][1][r]);
#pragma unroll
    for (int msk = 1; msk < 16; msk <<= 1)
#pragma unroll
      for (int rt = 0; rt < 2; ++rt)
#pragma unroll
        for (int r = 0; r < 4; ++r) pm[rt][r] = fmaxf(pm[rt][r], __shfl_xor(pm[rt][r], msk, 64));

    // defer-max (T13): only rescale when max grew by > 8
    int need = 0;
#pragma unroll
    for (int rt = 0; rt < 2; ++rt)
#pragma unroll
      for (int r = 0; r < 4; ++r) need |= (pm[rt][r] > mrow[rt][r] + 8.0f) ? 1 : 0;
    if (__any(need)) {
#pragma unroll
      for (int rt = 0; rt < 2; ++rt)
#pragma unroll
        for (int r = 0; r < 4; ++r) {
          float mn = fmaxf(mrow[rt][r], pm[rt][r]);
          float al = __expf(mrow[rt][r] - mn);
          mrow[rt][r] = mn;
          lrow[rt][r] *= al;
#pragma unroll
          for (int nt = 0; nt < 4; ++nt) o[rt][nt][r] *= al;
        }
    }

    // P = exp(S - m), row-sum
    float rs[2][4];
#pragma unroll
    for (int rt = 0; rt < 2; ++rt)
#pragma unroll
      for (int ct = 0; ct < 2; ++ct)
#pragma unroll
        for (int r = 0; r < 4; ++r)
          c[rt][ct][r] = __expf(c[rt][ct][r] - mrow[rt][r]);
#pragma unroll
    for (int rt = 0; rt < 2; ++rt)
#pragma unroll
      for (int r = 0; r < 4; ++r) rs[rt][r] = c[rt][0][r] + c[rt][1][r];
#pragma unroll
    for (int msk = 1; msk < 16; msk <<= 1)
#pragma unroll
      for (int rt = 0; rt < 2; ++rt)
#pragma unroll
        for (int r = 0; r < 4; ++r) rs[rt][r] += __shfl_xor(rs[rt][r], msk, 64);
#pragma unroll
    for (int rt = 0; rt < 2; ++rt)
#pragma unroll
      for (int r = 0; r < 4; ++r) lrow[rt][r] += rs[rt][r];

    // P through per-wave LDS: C-layout -> A-fragment layout (swizzled, no barrier)
    unsigned short* P = &Pt[wave][0];
#pragma unroll
    for (int rt = 0; rt < 2; ++rt)
#pragma unroll
      for (int r = 0; r < 4; ++r) {
        int row = rt * 16 + g * 4 + r;
        int sw = (row >> 1) & 3;
#pragma unroll
        for (int ct = 0; ct < 2; ++ct) {
          int col = ct * 16 + cl;
          P[row * 32 + (((col >> 3) ^ sw) << 3) + (col & 7)] = f2bf(c[rt][ct][r]);
        }
      }
    bf16x8 ap[2];
#pragma unroll
    for (int rt = 0; rt < 2; ++rt) {
      int row = rt * 16 + cl;
      ap[rt] = load8(&P[row * 32 + ((g ^ ((row >> 1) & 3)) << 3)]);
    }
    // PV: o += P[32x32] * V[32x64]
#pragma unroll
    for (int rt = 0; rt < 2; ++rt)
#pragma unroll
      for (int nt = 0; nt < 4; ++nt)
        o[rt][nt] = __builtin_amdgcn_mfma_f32_16x16x32_bf16(ap[rt], bv[nt], o[rt][nt], 0, 0, 0);
  }

  // normalize + write [B][S][H*64]
  const int b = bh >> 4, h = bh & 15;
#pragma unroll
  for (int rt = 0; rt < 2; ++rt)
#pragma unroll
    for (int r = 0; r < 4; ++r) {
      int q = qt + rt * 16 + g * 4 + r;
      float inv = 1.0f / lrow[rt][r];
      size_t base = ((size_t)(b * S_LEN + q)) * D_DIM + h * 64;
#pragma unroll
      for (int nt = 0; nt < 4; ++nt)
        Og[base + nt * 16 + cl] = f2bf(o[rt][nt][r] * inv);
    }
}

extern "C" void kernel_launch(void* const* d_in, const int* in_sizes, int n_in,
                              void* d_out, int out_size, void* d_ws, size_t ws_size,
                              hipStream_t stream) {
  const float* x  = (const float*)d_in[0];
  const float* Wq = (const float*)d_in[1];
  const float* Wk = (const float*)d_in[2];
  const float* Wv = (const float*)d_in[3];
  const float* Wo = (const float*)d_in[4];

  const int M = M_ROWS, D = D_DIM;

  unsigned short* ws  = (unsigned short*)d_ws;
  unsigned short* xb  = ws;                          // M*D
  unsigned short* wqb = xb  + (size_t)M * D;         // D*D
  unsigned short* wkb = wqb + (size_t)D * D;
  unsigned short* wvb = wkb + (size_t)D * D;
  unsigned short* wob = wvb + (size_t)D * D;
  unsigned short* qb  = wob + (size_t)D * D;         // M*D  [B,H,S,64] (scaled)
  unsigned short* kbf = qb  + (size_t)M * D;         // M*D  [B,H,S,64]
  unsigned short* vtb = kbf + (size_t)M * D;         // M*D  [B,H,64,S]
  unsigned short* aob = vtb + (size_t)M * D;         // M*D  [B,S,D]

  // 1) convert inputs to bf16 (single fused launch)
  {
    dim3 gc(M * D / 4 / 256, 5);
    cvt5_kernel<<<gc, 256, 0, stream>>>(x, Wq, Wk, Wv, Wo,
                                        xb, wqb, wkb, wvb, wob,
                                        M * D / 4, D * D / 4);
  }

  // 2) fused QKV projections (Q scaled by 1/8 in epilogue)
  dim3 gq(D / 128, M / 128, 3);
  gemm_bt<<<gq, 256, 0, stream>>>(xb, wqb, wkb, wvb, qb, kbf, vtb, M, D, D, 1);

  // 3) causal flash attention (no staging, no barriers)
  attn_kernel<<<512, 256, 0, stream>>>(qb, kbf, vtb, aob);

  // 4) output projection -> fp32 d_out
  dim3 go(D / 128, M / 128, 1);
  gemm_bt<<<go, 256, 0, stream>>>(aob, wob, wob, wob, d_out, d_out, d_out, M, D, D, 0);
}

// Round 3
// 188.840 us; speedup vs baseline: 1.3686x; 1.0898x over previous
//
#include <hip/hip_runtime.h>
#include <hip/hip_bf16.h>

// Problem constants: B=2, S=2048, D=1024, H=16, dk=64
#define S_LEN 2048
#define D_DIM 1024
#define N_HEADS 16
#define M_ROWS 4096  // B*S

typedef __bf16 bf16x8 __attribute__((ext_vector_type(8)));
typedef float f32x4 __attribute__((ext_vector_type(4)));
typedef unsigned short ushortx8 __attribute__((ext_vector_type(8)));

__device__ __forceinline__ unsigned short f2bf(float f) {
  unsigned int u = __builtin_bit_cast(unsigned int, f);
  u += 0x7fffu + ((u >> 16) & 1u);   // RNE
  return (unsigned short)(u >> 16);
}

__device__ __forceinline__ bf16x8 load8(const unsigned short* p) {
  return __builtin_bit_cast(bf16x8, *(const ushortx8*)p);
}

__device__ __forceinline__ void gload16(const unsigned short* g, unsigned short* l) {
  __builtin_amdgcn_global_load_lds((const __attribute__((address_space(1))) void*)g,
                                   (__attribute__((address_space(3))) void*)l,
                                   16, 0, 0);
}

// ---------------- fp32 -> bf16 convert (fused: x + 4 weights) ----------------
__global__ void cvt5_kernel(const float* __restrict__ s0, const float* __restrict__ s1,
                            const float* __restrict__ s2, const float* __restrict__ s3,
                            const float* __restrict__ s4,
                            unsigned short* __restrict__ d0, unsigned short* __restrict__ d1,
                            unsigned short* __restrict__ d2, unsigned short* __restrict__ d3,
                            unsigned short* __restrict__ d4,
                            int n4x, int n4w) {
  const int y = blockIdx.y;
  const float* s = (y == 0) ? s0 : (y == 1) ? s1 : (y == 2) ? s2 : (y == 3) ? s3 : s4;
  unsigned short* d = (y == 0) ? d0 : (y == 1) ? d1 : (y == 2) ? d2 : (y == 3) ? d3 : d4;
  const int n4 = (y == 0) ? n4x : n4w;
  int i = blockIdx.x * blockDim.x + threadIdx.x;
  if (i < n4) {
    float4 f = ((const float4*)s)[i];
    unsigned short a = f2bf(f.x), b = f2bf(f.y), c = f2bf(f.z), dd = f2bf(f.w);
    unsigned long long packed = (unsigned long long)a | ((unsigned long long)b << 16)
                              | ((unsigned long long)c << 32) | ((unsigned long long)dd << 48);
    ((unsigned long long*)d)[i] = packed;
  }
}

// ---------------- bf16 GEMM: C = A[M,K] * B[N,K]^T ----------------
// mode 0: fp32 row-major [M][N] output
// mode 1: bf16 [B,H,S,64] output (Q,K); Q (z==0) pre-scaled by 1/sqrt(dk)
// mode 2: bf16 [B,H,64,S] output (V transposed)
__global__ __launch_bounds__(256) void gemm_bt(
    const unsigned short* __restrict__ A,
    const unsigned short* __restrict__ B0,
    const unsigned short* __restrict__ B1,
    const unsigned short* __restrict__ B2,
    void* __restrict__ C0, void* __restrict__ C1, void* __restrict__ C2,
    int M, int N, int K, int modesel)
{
  __shared__ __align__(16) unsigned short At[128 * 64];
  __shared__ __align__(16) unsigned short Bt[128 * 64];

  const int z = blockIdx.z;
  const unsigned short* Bp = (z == 0) ? B0 : (z == 1) ? B1 : B2;
  void* Cp = (z == 0) ? C0 : (z == 1) ? C1 : C2;
  const int mode = (modesel == 0) ? 0 : ((z == 2) ? 2 : 1);
  const float escale = (modesel == 1 && z == 0) ? 0.125f : 1.0f;

  const int tid = threadIdx.x;
  const int lane = tid & 63, wave = tid >> 6;
  const int bm = blockIdx.y * 128, bn = blockIdx.x * 128;
  const int wr = wave >> 1, wc = wave & 1;           // 2x2 wave grid, 64x64 each
  const int cl = lane & 15, g = lane >> 4;
  // staging: chunks of 512 elems (8 rows x 64 elems); pre-swizzled global slot
  const int ci = lane >> 3, si = lane & 7;
  const int sg = si ^ (ci & 7);

  f32x4 acc[4][4] = {};

  for (int kb = 0; kb < K; kb += 64) {
    __syncthreads();
#pragma unroll
    for (int cc = 0; cc < 4; ++cc) {
      int chunk = wave * 4 + cc;
      int row = chunk * 8 + ci;
      gload16(A  + (size_t)(bm + row) * K + kb + sg * 8, &At[chunk * 512]);
      gload16(Bp + (size_t)(bn + row) * K + kb + sg * 8, &Bt[chunk * 512]);
    }
    __syncthreads();
#pragma unroll
    for (int kc = 0; kc < 2; ++kc) {
      bf16x8 af[4], bfr[4];
#pragma unroll
      for (int mi = 0; mi < 4; ++mi) {
        int row = wr * 64 + mi * 16 + cl;
        int slot = (kc * 4 + g) ^ (row & 7);
        af[mi] = load8(&At[row * 64 + slot * 8]);
      }
#pragma unroll
      for (int ni = 0; ni < 4; ++ni) {
        int row = wc * 64 + ni * 16 + cl;
        int slot = (kc * 4 + g) ^ (row & 7);
        bfr[ni] = load8(&Bt[row * 64 + slot * 8]);
      }
#pragma unroll
      for (int mi = 0; mi < 4; ++mi)
#pragma unroll
        for (int ni = 0; ni < 4; ++ni)
          acc[mi][ni] = __builtin_amdgcn_mfma_f32_16x16x32_bf16(af[mi], bfr[ni], acc[mi][ni], 0, 0, 0);
    }
  }

  // epilogue: C row = (lane>>4)*4 + reg, col = lane&15
  const int r0 = g * 4;
#pragma unroll
  for (int mi = 0; mi < 4; ++mi) {
#pragma unroll
    for (int ni = 0; ni < 4; ++ni) {
      int mg = bm + wr * 64 + mi * 16 + r0;
      int ng = bn + wc * 64 + ni * 16 + cl;
#pragma unroll
      for (int r = 0; r < 4; ++r) {
        float v = acc[mi][ni][r] * escale;
        int m = mg + r;
        if (mode == 0) {
          ((float*)Cp)[(size_t)m * N + ng] = v;
        } else {
          int b = m >> 11, s = m & 2047;        // S=2048
          int h = ng >> 6, d = ng & 63;         // dk=64
          unsigned short* o = (unsigned short*)Cp;
          if (mode == 1) o[((size_t)(b * N_HEADS + h) * S_LEN + s) * 64 + d] = f2bf(v);
          else           o[((size_t)(b * N_HEADS + h) * 64 + d) * S_LEN + s] = f2bf(v);
        }
      }
    }
  }
}

// ---------------- causal flash attention: swapped-QK, no barriers ------------
// Q,K: [BH][S][64] bf16 (Q pre-scaled); Vt: [BH][64][S] bf16; out: [B][S][H*64] bf16
// 512 blocks x 256 thr; each wave independent: 32 q-rows, 32-key blocks.
#define PSTR 40   // padded P row stride (elems) -> 80B rows, bank-friendly

__global__ __launch_bounds__(256) void attn_kernel(
    const unsigned short* __restrict__ Qg,
    const unsigned short* __restrict__ Kg,
    const unsigned short* __restrict__ Vtg,
    unsigned short* __restrict__ Og)
{
  __shared__ __align__(16) unsigned short Pt[4][32 * PSTR];  // per-wave P buffer
  __shared__ float Af[4][32];                                // per-wave alpha/inv transpose

  const int tid = threadIdx.x;
  const int lane = tid & 63, wave = tid >> 6;
  const int cl = lane & 15, g = lane >> 4;

  // XCD-contiguous swizzle; heavy q-chunks first within each XCD
  const int wg = (blockIdx.x & 7) * 64 + (blockIdx.x >> 3);
  const int bh = wg >> 4;               // 32 (b,h) pairs, 4 per XCD
  const int qc = 15 - (wg & 15);        // descending work order
  const int qt = qc * 128 + wave * 32;

  const size_t qkb = (size_t)bh * S_LEN;
  unsigned short* P = &Pt[wave][0];
  float* AF = &Af[wave][0];

  // Q fragments in registers for the whole kernel (already scaled by 1/8)
  bf16x8 aq[2][2];
#pragma unroll
  for (int rt = 0; rt < 2; ++rt)
#pragma unroll
    for (int kh = 0; kh < 2; ++kh)
      aq[rt][kh] = load8(Qg + (qkb + qt + rt * 16 + cl) * 64 + kh * 32 + g * 8);

  f32x4 o[2][4] = {};
  float mrow[2] = {-1e30f, -1e30f};
  float lrow[2] = {0.f, 0.f};

  const int nkb = qt / 32 + 1;

  // K fragment double-buffer (prefetch across iterations)
  bf16x8 kc[2][2], kn[2][2];
#pragma unroll
  for (int ct = 0; ct < 2; ++ct)
#pragma unroll
    for (int kh = 0; kh < 2; ++kh)
      kc[ct][kh] = load8(Kg + (qkb + ct * 16 + cl) * 64 + kh * 32 + g * 8);

  for (int kb = 0; kb < nkb; ++kb) {
    const int kbase = kb * 32;

    // V^T fragments for THIS block (used far below -> latency hidden)
    bf16x8 bv[4];
#pragma unroll
    for (int nt = 0; nt < 4; ++nt)
      bv[nt] = load8(Vtg + ((size_t)bh * 64 + nt * 16 + cl) * S_LEN + kbase + g * 8);
    // prefetch K for next block
    {
      int nb = (kb + 1 < nkb) ? kbase + 32 : kbase;
#pragma unroll
      for (int ct = 0; ct < 2; ++ct)
#pragma unroll
        for (int kh = 0; kh < 2; ++kh)
          kn[ct][kh] = load8(Kg + (qkb + nb + ct * 16 + cl) * 64 + kh * 32 + g * 8);
    }

    // swapped scores: Ct[k][q] = K·Q^T; lane holds q=rt*16+cl, k=ct*16+g*4+r
    f32x4 c[2][2] = {};
#pragma unroll
    for (int rt = 0; rt < 2; ++rt)
#pragma unroll
      for (int ct = 0; ct < 2; ++ct) {
        c[rt][ct] = __builtin_amdgcn_mfma_f32_16x16x32_bf16(kc[ct][0], aq[rt][0], c[rt][ct], 0, 0, 0);
        c[rt][ct] = __builtin_amdgcn_mfma_f32_16x16x32_bf16(kc[ct][1], aq[rt][1], c[rt][ct], 0, 0, 0);
      }

    if (kb == nkb - 1) {   // diagonal block: causal mask (k > q -> -inf)
#pragma unroll
      for (int rt = 0; rt < 2; ++rt) {
        int q = qt + rt * 16 + cl;
#pragma unroll
        for (int ct = 0; ct < 2; ++ct) {
          int k0 = kbase + ct * 16 + g * 4;
#pragma unroll
          for (int r = 0; r < 4; ++r)
            if (k0 + r > q) c[rt][ct][r] = -1e30f;
        }
      }
    }

    // row max over k: in-register (8 vals) + 2-step butterfly over g-groups
    float pm[2];
#pragma unroll
    for (int rt = 0; rt < 2; ++rt) {
      float a0 = fmaxf(fmaxf(c[rt][0][0], c[rt][0][1]), fmaxf(c[rt][0][2], c[rt][0][3]));
      float a1 = fmaxf(fmaxf(c[rt][1][0], c[rt][1][1]), fmaxf(c[rt][1][2], c[rt][1][3]));
      pm[rt] = fmaxf(a0, a1);
    }
#pragma unroll
    for (int msk = 16; msk < 64; msk <<= 1)
#pragma unroll
      for (int rt = 0; rt < 2; ++rt) pm[rt] = fmaxf(pm[rt], __shfl_xor(pm[rt], msk, 64));

    // defer-max (T13): only rescale O when max grew by > 8
    int need = (pm[0] > mrow[0] + 8.0f) | (pm[1] > mrow[1] + 8.0f);
    if (__any(need)) {
      float al[2];
#pragma unroll
      for (int rt = 0; rt < 2; ++rt) {
        float mn = fmaxf(mrow[rt], pm[rt]);
        al[rt] = __expf(mrow[rt] - mn);
        mrow[rt] = mn;
        lrow[rt] *= al[rt];
      }
      if (g == 0) { AF[cl] = al[0]; AF[16 + cl] = al[1]; }
      __builtin_amdgcn_s_waitcnt(0);   // lgkmcnt drain (wave-local LDS RAW)
#pragma unroll
      for (int rt = 0; rt < 2; ++rt) {
        f32x4 alT = *(const f32x4*)&AF[rt * 16 + g * 4];
#pragma unroll
        for (int nt = 0; nt < 4; ++nt)
#pragma unroll
          for (int r = 0; r < 4; ++r) o[rt][nt][r] *= alT[r];
      }
    }

    // P = exp(S - m); row-sum over k (in-register + 2-step butterfly)
    float rs[2];
#pragma unroll
    for (int rt = 0; rt < 2; ++rt) {
#pragma unroll
      for (int ct = 0; ct < 2; ++ct)
#pragma unroll
        for (int r = 0; r < 4; ++r)
          c[rt][ct][r] = __expf(c[rt][ct][r] - mrow[rt]);
      rs[rt] = (c[rt][0][0] + c[rt][0][1]) + (c[rt][0][2] + c[rt][0][3])
             + (c[rt][1][0] + c[rt][1][1]) + (c[rt][1][2] + c[rt][1][3]);
    }
#pragma unroll
    for (int msk = 16; msk < 64; msk <<= 1)
#pragma unroll
      for (int rt = 0; rt < 2; ++rt) rs[rt] += __shfl_xor(rs[rt], msk, 64);
#pragma unroll
    for (int rt = 0; rt < 2; ++rt) lrow[rt] += rs[rt];

    // P^T -> LDS: 4 contiguous k per lane = one b64 write per (rt,ct)
#pragma unroll
    for (int rt = 0; rt < 2; ++rt)
#pragma unroll
      for (int ct = 0; ct < 2; ++ct) {
        unsigned long long pk =
            (unsigned long long)f2bf(c[rt][ct][0])
          | ((unsigned long long)f2bf(c[rt][ct][1]) << 16)
          | ((unsigned long long)f2bf(c[rt][ct][2]) << 32)
          | ((unsigned long long)f2bf(c[rt][ct][3]) << 48);
        *(unsigned long long*)&P[(rt * 16 + cl) * PSTR + ct * 16 + g * 4] = pk;
      }
    // read back as PV A-fragments (compiler inserts lgkmcnt)
    bf16x8 ap[2];
#pragma unroll
    for (int rt = 0; rt < 2; ++rt)
      ap[rt] = load8(&P[(rt * 16 + cl) * PSTR + g * 8]);

    // PV: o += P[32x32] * V[32x64]
#pragma unroll
    for (int rt = 0; rt < 2; ++rt)
#pragma unroll
      for (int nt = 0; nt < 4; ++nt)
        o[rt][nt] = __builtin_amdgcn_mfma_f32_16x16x32_bf16(ap[rt], bv[nt], o[rt][nt], 0, 0, 0);

    // rotate K double-buffer
#pragma unroll
    for (int ct = 0; ct < 2; ++ct)
#pragma unroll
      for (int kh = 0; kh < 2; ++kh) kc[ct][kh] = kn[ct][kh];
  }

  // final 1/l, transposed to O layout via LDS
  if (g == 0) { AF[cl] = 1.0f / lrow[0]; AF[16 + cl] = 1.0f / lrow[1]; }
  __builtin_amdgcn_s_waitcnt(0);
  const int b = bh >> 4, h = bh & 15;
#pragma unroll
  for (int rt = 0; rt < 2; ++rt) {
    f32x4 invT = *(const f32x4*)&AF[rt * 16 + g * 4];
#pragma unroll
    for (int r = 0; r < 4; ++r) {
      int q = qt + rt * 16 + g * 4 + r;
      size_t base = ((size_t)(b * S_LEN + q)) * D_DIM + h * 64;
#pragma unroll
      for (int nt = 0; nt < 4; ++nt)
        Og[base + nt * 16 + cl] = f2bf(o[rt][nt][r] * invT[r]);
    }
  }
}

extern "C" void kernel_launch(void* const* d_in, const int* in_sizes, int n_in,
                              void* d_out, int out_size, void* d_ws, size_t ws_size,
                              hipStream_t stream) {
  const float* x  = (const float*)d_in[0];
  const float* Wq = (const float*)d_in[1];
  const float* Wk = (const float*)d_in[2];
  const float* Wv = (const float*)d_in[3];
  const float* Wo = (const float*)d_in[4];

  const int M = M_ROWS, D = D_DIM;

  unsigned short* ws  = (unsigned short*)d_ws;
  unsigned short* xb  = ws;                          // M*D
  unsigned short* wqb = xb  + (size_t)M * D;         // D*D
  unsigned short* wkb = wqb + (size_t)D * D;
  unsigned short* wvb = wkb + (size_t)D * D;
  unsigned short* wob = wvb + (size_t)D * D;
  unsigned short* qb  = wob + (size_t)D * D;         // M*D  [B,H,S,64] (scaled)
  unsigned short* kbf = qb  + (size_t)M * D;         // M*D  [B,H,S,64]
  unsigned short* vtb = kbf + (size_t)M * D;         // M*D  [B,H,64,S]
  unsigned short* aob = vtb + (size_t)M * D;         // M*D  [B,S,D]

  // 1) convert inputs to bf16 (single fused launch)
  {
    dim3 gc(M * D / 4 / 256, 5);
    cvt5_kernel<<<gc, 256, 0, stream>>>(x, Wq, Wk, Wv, Wo,
                                        xb, wqb, wkb, wvb, wob,
                                        M * D / 4, D * D / 4);
  }

  // 2) fused QKV projections (Q scaled by 1/8 in epilogue)
  dim3 gq(D / 128, M / 128, 3);
  gemm_bt<<<gq, 256, 0, stream>>>(xb, wqb, wkb, wvb, qb, kbf, vtb, M, D, D, 1);

  // 3) causal flash attention (swapped-QK, prefetch, no barriers)
  attn_kernel<<<512, 256, 0, stream>>>(qb, kbf, vtb, aob);

  // 4) output projection -> fp32 d_out
  dim3 go(D / 128, M / 128, 1);
  gemm_bt<<<go, 256, 0, stream>>>(aob, wob, wob, wob, d_out, d_out, d_out, M, D, D, 0);
}